// Round 2
// baseline (501.288 us; speedup 1.0000x reference)
//
#include <hip/hip_runtime.h>
#include <math.h>

// Problem constants
#define B 32
#define N 4096
#define D 128
#define KTOP 512
#define NPB 2048
#define MSEG (B * NPB)      // 65536
#define E (B * N)           // 131072
#define MAXC 32             // max edges per segment (Binomial(4096,1/2048), mean 2)

// ---------------------------------------------------------------------------
// K0: per-batch precompute (fp64): query = cat(qh,qr,qt)@W_q+b_q,
// u_d = q_d*W1_d - W2_d + W3_d, v = W_a @ u, c2 = q.(W2+W3)+b_att+b_a.u
// Emits fp32 copies (vf, c2f) for the streaming kernel.
// ---------------------------------------------------------------------------
__global__ __launch_bounds__(128) void k0_precompute(
    const float* __restrict__ qh, const float* __restrict__ qr,
    const float* __restrict__ qt, const float* __restrict__ Wq,
    const float* __restrict__ bq, const float* __restrict__ Wa,
    const float* __restrict__ ba, const float* __restrict__ Watt,
    const float* __restrict__ batt, double* __restrict__ vws,
    double* __restrict__ c2ws, float* __restrict__ vf,
    float* __restrict__ c2f) {
  int b = blockIdx.x, d = threadIdx.x;
  __shared__ double u[128];
  __shared__ double red[128];
  const float* qhb = qh + b * 128;
  const float* qrb = qr + b * 128;
  const float* qtb = qt + b * 128;
  double acc = (double)bq[d];
  for (int i = 0; i < 128; ++i) acc += (double)qhb[i] * (double)Wq[i * 128 + d];
  for (int i = 0; i < 128; ++i) acc += (double)qrb[i] * (double)Wq[(128 + i) * 128 + d];
  for (int i = 0; i < 128; ++i) acc += (double)qtb[i] * (double)Wq[(256 + i) * 128 + d];
  double w1 = (double)Watt[d], w2 = (double)Watt[128 + d], w3 = (double)Watt[256 + d];
  double ud = acc * w1 - w2 + w3;
  u[d] = ud;
  red[d] = acc * (w2 + w3) + (double)ba[d] * ud;
  __syncthreads();
  for (int s = 64; s > 0; s >>= 1) {
    if (d < s) red[d] += red[d + s];
    __syncthreads();
  }
  if (d == 0) {
    double c2 = red[0] + (double)batt[0];
    c2ws[b] = c2;
    c2f[b] = (float)c2;
  }
  for (int i = d; i < 384; i += 128) {
    double vv = 0.0;
    for (int dd = 0; dd < 128; ++dd) vv += (double)Wa[i * 128 + dd] * u[dd];
    vws[b * 384 + i] = vv;
    vf[b * 384 + i] = (float)vv;
  }
}

// ---------------------------------------------------------------------------
// K1: per-edge attention, fp32. 32 lanes per edge, float4 per lane.
// Block of 256 covers 64 consecutive edges (8 half-waves x 8 iters), all the
// same batch (64 | 4096), so v/wr stay in registers for the whole block.
// att[e] = 0.5*(sigmoid(r.v0+t.v1+tm.v2+c2_b) + sigmoid(h.Wrule+brule))
// ---------------------------------------------------------------------------
__global__ __launch_bounds__(256) void k1_att(
    const float* __restrict__ r, const float* __restrict__ t,
    const float* __restrict__ tm, const float* __restrict__ hidden,
    const float* __restrict__ Wrule, const float* __restrict__ brule,
    const float* __restrict__ vf, const float* __restrict__ c2f,
    float* __restrict__ attw) {
  int tid = threadIdx.x;
  int h = tid >> 5;       // half-wave id 0..7
  int l = tid & 31;       // lane within 32
  int base = blockIdx.x * 64;
  int b = base >> 12;     // batch (uniform over block)
  const float4* vb = (const float4*)(vf + b * 384);
  float4 v0 = vb[l];
  float4 v1 = vb[32 + l];
  float4 v2 = vb[64 + l];
  float4 wr = ((const float4*)Wrule)[l];
  float c2 = c2f[b];
  float br = brule[0];
#pragma unroll 4
  for (int i = 0; i < 8; ++i) {
    int e = base + i * 8 + h;
    size_t eo = (size_t)e * 128 + l * 4;
    float4 ra = *(const float4*)(r + eo);
    float4 ta = *(const float4*)(t + eo);
    float4 ma = *(const float4*)(tm + eo);
    float4 ha = *(const float4*)(hidden + eo);
    float p1 = ra.x * v0.x + ra.y * v0.y + ra.z * v0.z + ra.w * v0.w;
    p1 += ta.x * v1.x + ta.y * v1.y + ta.z * v1.z + ta.w * v1.w;
    p1 += ma.x * v2.x + ma.y * v2.y + ma.z * v2.z + ma.w * v2.w;
    float p2 = ha.x * wr.x + ha.y * wr.y + ha.z * wr.z + ha.w * wr.w;
#pragma unroll
    for (int off = 16; off > 0; off >>= 1) {
      p1 += __shfl_xor(p1, off);
      p2 += __shfl_xor(p2, off);
    }
    if (l == 0) {
      float a1 = 1.0f / (1.0f + expf(-(p1 + c2)));
      float a2 = 1.0f / (1.0f + expf(-(p2 + br)));
      attw[e] = 0.5f * (a1 + a2);
    }
  }
}

// ---------------------------------------------------------------------------
// KB: build fixed-stride per-segment edge lists via atomics.
// ---------------------------------------------------------------------------
__global__ __launch_bounds__(256) void kb_build(const int* __restrict__ tidx,
                                                int* __restrict__ counts,
                                                int* __restrict__ lists) {
  int e = blockIdx.x * 256 + threadIdx.x;
  int m = tidx[e];
  int pos = atomicAdd(&counts[m], 1);
  if (pos < MAXC) lists[m * MAXC + pos] = e;
}

// ---------------------------------------------------------------------------
// K_AGG: agg_att[m] = sum of attw over segment's edges (tiny).
// ---------------------------------------------------------------------------
__global__ __launch_bounds__(256) void k_agg(const int* __restrict__ counts,
                                             const int* __restrict__ lists,
                                             const float* __restrict__ attw,
                                             float* __restrict__ agg_att) {
  int m = blockIdx.x * 256 + threadIdx.x;
  int cnt = counts[m];
  if (cnt > MAXC) cnt = MAXC;
  float s = 0.f;
  for (int j = 0; j < cnt; ++j) s += attw[lists[m * MAXC + j]];
  agg_att[m] = s;
}

// ---------------------------------------------------------------------------
// K6: exact top-K by rank counting. Block = (batch, chunk of 256 elems).
// rank(i) = #{j : v_j > v_i || (v_j == v_i && j < i)}  == lax.top_k position.
// ---------------------------------------------------------------------------
__global__ __launch_bounds__(256) void k6_topk(
    const float* __restrict__ agg_att, const int* __restrict__ tail_nodes,
    float* __restrict__ out_nodes, int* __restrict__ idxw) {
  __shared__ float sv[2048];
  int b = blockIdx.x >> 3;
  int chunk = blockIdx.x & 7;
  int tid = threadIdx.x;
  for (int s = tid; s < 2048; s += 256) sv[s] = agg_att[b * 2048 + s];
  __syncthreads();
  int i = chunk * 256 + tid;
  float vi = sv[i];
  int rank = 0;
#pragma unroll 8
  for (int j = 0; j < 2048; ++j) {
    float vj = sv[j];
    rank += (vj > vi) || (vj == vi && j < i);
  }
  if (rank < KTOP) {
    int gm = b * 2048 + i;
    int p = b * KTOP + rank;
    out_nodes[p * 2 + 0] = (float)tail_nodes[gm * 3 + 1];
    out_nodes[p * 2 + 1] = (float)tail_nodes[gm * 3 + 2];
    idxw[p] = gm;
  }
}

// ---------------------------------------------------------------------------
// K7: for selected rows only — gather edges, fused segment-sum of message/
// hidden, then out_emd = accT @ W_out + b_out (W_out staged in LDS).
// 512 blocks x 32 rows, 2 rows in flight per block.
// ---------------------------------------------------------------------------
__global__ __launch_bounds__(256) void k7_out(
    const float* __restrict__ tail_emd, const float* __restrict__ r,
    const float* __restrict__ tm, const float* __restrict__ hidden,
    const float* __restrict__ qh, const float* __restrict__ attw,
    const int* __restrict__ counts, const int* __restrict__ lists,
    const float* __restrict__ Wout, const float* __restrict__ bout,
    const int* __restrict__ idxw, float* __restrict__ out_emd,
    float* __restrict__ out_hid) {
  __shared__ float Ws[16384];
  __shared__ float es[256];
  int tid = threadIdx.x;
  int sub = tid >> 7, d = tid & 127;
  for (int i = tid; i < 16384; i += 256) Ws[i] = Wout[i];
  int base = blockIdx.x * 32;
  float bo = bout[d];
  for (int j = 0; j < 32; j += 2) {
    int row = base + j + sub;
    int m = idxw[row];
    int b = m >> 11;
    int cnt = counts[m];
    if (cnt > MAXC) cnt = MAXC;
    float accT = tail_emd[(size_t)m * 128 + d];
    float accH = 0.f;
    float qhd = qh[b * 128 + d];
    for (int jj = 0; jj < cnt; ++jj) {
      int e = lists[m * MAXC + jj];
      float a = attw[e];
      size_t eo = (size_t)e * 128 + d;
      accT += a * (qhd + r[eo] + tm[eo]);
      accH += hidden[eo];
    }
    __syncthreads();
    es[sub * 128 + d] = accT;
    __syncthreads();
    float acc = bo;
#pragma unroll 8
    for (int i = 0; i < 128; ++i) acc += es[sub * 128 + i] * Ws[i * 128 + d];
    out_emd[(size_t)row * 128 + d] = acc;
    out_hid[(size_t)row * 128 + d] = accH;
  }
}

// ---------------------------------------------------------------------------
extern "C" void kernel_launch(void* const* d_in, const int* in_sizes, int n_in,
                              void* d_out, int out_size, void* d_ws,
                              size_t ws_size, hipStream_t stream) {
  const float* q_head = (const float*)d_in[0];
  const float* q_rel = (const float*)d_in[1];
  const float* q_time = (const float*)d_in[2];
  const float* r_nb = (const float*)d_in[3];
  const float* t_nb = (const float*)d_in[4];
  const float* tm_nb = (const float*)d_in[5];
  const float* hidden = (const float*)d_in[6];
  const float* tail_emd = (const float*)d_in[7];
  const int* tail_index = (const int*)d_in[8];
  const int* tail_nodes = (const int*)d_in[9];
  const float* W_q = (const float*)d_in[10];
  const float* b_q = (const float*)d_in[11];
  const float* W_a = (const float*)d_in[12];
  const float* b_a = (const float*)d_in[13];
  const float* W_att = (const float*)d_in[14];
  const float* b_att = (const float*)d_in[15];
  const float* W_rule = (const float*)d_in[16];
  const float* b_rule = (const float*)d_in[17];
  const float* W_out = (const float*)d_in[18];
  const float* b_out = (const float*)d_in[19];

  char* ws = (char*)d_ws;
  double* vws = (double*)(ws + 0);           // 32*384*8 = 98304
  double* c2ws = (double*)(ws + 98304);      // 256
  float* vf = (float*)(ws + 98560);          // 32*384*4 = 49152
  float* c2f = (float*)(ws + 147712);        // 128 (pad to 147968)
  float* attw = (float*)(ws + 147968);       // E*4 = 524288
  int* counts = (int*)(ws + 672256);         // M*4 = 262144
  int* lists = (int*)(ws + 934400);          // M*32*4 = 8388608
  float* agg_att = (float*)(ws + 9323008);   // M*4 = 262144
  int* idxw = (int*)(ws + 9585152);          // B*K*4 = 65536  (end 9650688)

  float* out_nodes = (float*)d_out;                       // B*K*2
  float* out_emd = (float*)d_out + (size_t)B * KTOP * 2;  // B*K*128
  float* out_hid = out_emd + (size_t)B * KTOP * 128;      // B*K*128

  hipMemsetAsync(counts, 0, MSEG * sizeof(int), stream);
  k0_precompute<<<B, 128, 0, stream>>>(q_head, q_rel, q_time, W_q, b_q, W_a,
                                       b_a, W_att, b_att, vws, c2ws, vf, c2f);
  k1_att<<<E / 64, 256, 0, stream>>>(r_nb, t_nb, tm_nb, hidden, W_rule, b_rule,
                                     vf, c2f, attw);
  kb_build<<<E / 256, 256, 0, stream>>>(tail_index, counts, lists);
  k_agg<<<MSEG / 256, 256, 0, stream>>>(counts, lists, attw, agg_att);
  k6_topk<<<B * 8, 256, 0, stream>>>(agg_att, tail_nodes, out_nodes, idxw);
  k7_out<<<(B * KTOP) / 32, 256, 0, stream>>>(tail_emd, r_nb, tm_nb, hidden,
                                              q_head, attw, counts, lists,
                                              W_out, b_out, idxw, out_emd,
                                              out_hid);
}

// Round 3
// 461.873 us; speedup vs baseline: 1.0853x; 1.0853x over previous
//
#include <hip/hip_runtime.h>
#include <math.h>

// Problem constants
#define B 32
#define N 4096
#define D 128
#define KTOP 512
#define NPB 2048
#define MSEG (B * NPB)      // 65536
#define E (B * N)           // 131072
#define MAXC 32             // max edges per segment (Binomial(4096,1/2048), mean 2)
#define K7ROWS 16           // rows per k7 block

// ---------------------------------------------------------------------------
// K0: per-batch precompute (fp64): query = cat(qh,qr,qt)@W_q+b_q,
// u_d = q_d*W1_d - W2_d + W3_d, v = W_a @ u, c2 = q.(W2+W3)+b_att+b_a.u
// Unrolled x4 with independent partials to break dependent fp64 chains.
// ---------------------------------------------------------------------------
__global__ __launch_bounds__(128) void k0_precompute(
    const float* __restrict__ qh, const float* __restrict__ qr,
    const float* __restrict__ qt, const float* __restrict__ Wq,
    const float* __restrict__ bq, const float* __restrict__ Wa,
    const float* __restrict__ ba, const float* __restrict__ Watt,
    const float* __restrict__ batt, float* __restrict__ vf,
    float* __restrict__ c2f) {
  int b = blockIdx.x, d = threadIdx.x;
  __shared__ double u[128];
  __shared__ double red[128];
  const float* qhb = qh + b * 128;
  const float* qrb = qr + b * 128;
  const float* qtb = qt + b * 128;
  double a0 = 0, a1 = 0, a2 = 0, a3 = 0;
#pragma unroll 4
  for (int i = 0; i < 128; i += 4) {
    a0 += (double)qhb[i] * (double)Wq[i * 128 + d];
    a1 += (double)qhb[i + 1] * (double)Wq[(i + 1) * 128 + d];
    a2 += (double)qhb[i + 2] * (double)Wq[(i + 2) * 128 + d];
    a3 += (double)qhb[i + 3] * (double)Wq[(i + 3) * 128 + d];
  }
#pragma unroll 4
  for (int i = 0; i < 128; i += 4) {
    a0 += (double)qrb[i] * (double)Wq[(128 + i) * 128 + d];
    a1 += (double)qrb[i + 1] * (double)Wq[(129 + i) * 128 + d];
    a2 += (double)qrb[i + 2] * (double)Wq[(130 + i) * 128 + d];
    a3 += (double)qrb[i + 3] * (double)Wq[(131 + i) * 128 + d];
  }
#pragma unroll 4
  for (int i = 0; i < 128; i += 4) {
    a0 += (double)qtb[i] * (double)Wq[(256 + i) * 128 + d];
    a1 += (double)qtb[i + 1] * (double)Wq[(257 + i) * 128 + d];
    a2 += (double)qtb[i + 2] * (double)Wq[(258 + i) * 128 + d];
    a3 += (double)qtb[i + 3] * (double)Wq[(259 + i) * 128 + d];
  }
  double acc = (double)bq[d] + ((a0 + a1) + (a2 + a3));
  double w1 = (double)Watt[d], w2 = (double)Watt[128 + d], w3 = (double)Watt[256 + d];
  double ud = acc * w1 - w2 + w3;
  u[d] = ud;
  red[d] = acc * (w2 + w3) + (double)ba[d] * ud;
  __syncthreads();
  for (int s = 64; s > 0; s >>= 1) {
    if (d < s) red[d] += red[d + s];
    __syncthreads();
  }
  if (d == 0) c2f[b] = (float)(red[0] + (double)batt[0]);
  for (int i = d; i < 384; i += 128) {
    double v0 = 0, v1 = 0, v2 = 0, v3 = 0;
#pragma unroll 4
    for (int dd = 0; dd < 128; dd += 4) {
      v0 += (double)Wa[i * 128 + dd] * u[dd];
      v1 += (double)Wa[i * 128 + dd + 1] * u[dd + 1];
      v2 += (double)Wa[i * 128 + dd + 2] * u[dd + 2];
      v3 += (double)Wa[i * 128 + dd + 3] * u[dd + 3];
    }
    vf[b * 384 + i] = (float)((v0 + v1) + (v2 + v3));
  }
}

// ---------------------------------------------------------------------------
// K1: per-edge attention, fp32. 32 lanes per edge, float4 per lane.
// Also accumulates agg_att[m] as fp64 atomics (order-independent to ~1e-15,
// far below the rank-512 boundary gap ~1e-3 -> ranking stable).
// ---------------------------------------------------------------------------
__global__ __launch_bounds__(256) void k1_att(
    const float* __restrict__ r, const float* __restrict__ t,
    const float* __restrict__ tm, const float* __restrict__ hidden,
    const float* __restrict__ Wrule, const float* __restrict__ brule,
    const float* __restrict__ vf, const float* __restrict__ c2f,
    const int* __restrict__ tidx, float* __restrict__ attw,
    double* __restrict__ aggd) {
  int tid = threadIdx.x;
  int h = tid >> 5;       // half-wave id 0..7
  int l = tid & 31;       // lane within 32
  int base = blockIdx.x * 64;
  int b = base >> 12;     // batch (uniform over block)
  const float4* vb = (const float4*)(vf + b * 384);
  float4 v0 = vb[l];
  float4 v1 = vb[32 + l];
  float4 v2 = vb[64 + l];
  float4 wr = ((const float4*)Wrule)[l];
  float c2 = c2f[b];
  float br = brule[0];
#pragma unroll 4
  for (int i = 0; i < 8; ++i) {
    int e = base + i * 8 + h;
    size_t eo = (size_t)e * 128 + l * 4;
    float4 ra = *(const float4*)(r + eo);
    float4 ta = *(const float4*)(t + eo);
    float4 ma = *(const float4*)(tm + eo);
    float4 ha = *(const float4*)(hidden + eo);
    float p1 = ra.x * v0.x + ra.y * v0.y + ra.z * v0.z + ra.w * v0.w;
    p1 += ta.x * v1.x + ta.y * v1.y + ta.z * v1.z + ta.w * v1.w;
    p1 += ma.x * v2.x + ma.y * v2.y + ma.z * v2.z + ma.w * v2.w;
    float p2 = ha.x * wr.x + ha.y * wr.y + ha.z * wr.z + ha.w * wr.w;
#pragma unroll
    for (int off = 16; off > 0; off >>= 1) {
      p1 += __shfl_xor(p1, off);
      p2 += __shfl_xor(p2, off);
    }
    if (l == 0) {
      float a1 = 1.0f / (1.0f + expf(-(p1 + c2)));
      float a2 = 1.0f / (1.0f + expf(-(p2 + br)));
      float a = 0.5f * (a1 + a2);
      attw[e] = a;
      atomicAdd(&aggd[tidx[e]], (double)a);
    }
  }
}

// ---------------------------------------------------------------------------
// KB: build fixed-stride per-segment edge lists via atomics.
// ---------------------------------------------------------------------------
__global__ __launch_bounds__(256) void kb_build(const int* __restrict__ tidx,
                                                int* __restrict__ counts,
                                                int* __restrict__ lists) {
  int e = blockIdx.x * 256 + threadIdx.x;
  int m = tidx[e];
  int pos = atomicAdd(&counts[m], 1);
  if (pos < MAXC) lists[m * MAXC + pos] = e;
}

// ---------------------------------------------------------------------------
// K6: exact top-K by rank counting on fp64 agg. Block = (batch, 256 elems).
// rank(i) = #{j : v_j > v_i || (v_j == v_i && j < i)}  == lax.top_k position.
// ---------------------------------------------------------------------------
__global__ __launch_bounds__(256) void k6_topk(
    const double* __restrict__ aggd, const int* __restrict__ tail_nodes,
    float* __restrict__ out_nodes, int* __restrict__ idxw) {
  __shared__ double sv[2048];
  int b = blockIdx.x >> 3;
  int chunk = blockIdx.x & 7;
  int tid = threadIdx.x;
  for (int s = tid; s < 2048; s += 256) sv[s] = aggd[b * 2048 + s];
  __syncthreads();
  int i = chunk * 256 + tid;
  double vi = sv[i];
  int rank = 0;
#pragma unroll 8
  for (int j = 0; j < 2048; ++j) {
    double vj = sv[j];
    rank += (vj > vi) || (vj == vi && j < i);
  }
  if (rank < KTOP) {
    int gm = b * 2048 + i;
    int p = b * KTOP + rank;
    out_nodes[p * 2 + 0] = (float)tail_nodes[gm * 3 + 1];
    out_nodes[p * 2 + 1] = (float)tail_nodes[gm * 3 + 2];
    idxw[p] = gm;
  }
}

// ---------------------------------------------------------------------------
// K7: selected rows only. Phase 1: gather edges, segment-sum message/hidden
// into LDS es[16][128] (+out_hid). Phase 2: out_emd = es @ W_out + b_out with
// W_out from L2 (64 KB, broadcast reads) and 8 independent accs/thread.
// Grid 1024 x 256, LDS 8 KB -> high occupancy, no long dependent chains.
// ---------------------------------------------------------------------------
__global__ __launch_bounds__(256) void k7_out(
    const float* __restrict__ tail_emd, const float* __restrict__ r,
    const float* __restrict__ tm, const float* __restrict__ hidden,
    const float* __restrict__ qh, const float* __restrict__ attw,
    const int* __restrict__ counts, const int* __restrict__ lists,
    const float* __restrict__ Wout, const float* __restrict__ bout,
    const int* __restrict__ idxw, float* __restrict__ out_emd,
    float* __restrict__ out_hid) {
  __shared__ float es[K7ROWS][128];
  int tid = threadIdx.x;
  int sub = tid >> 7, d = tid & 127;
  int base = blockIdx.x * K7ROWS;
  // ---- phase 1: gather + segment sums ----
  for (int j = 0; j < K7ROWS; j += 2) {
    int row = base + j + sub;
    int m = idxw[row];
    int b = m >> 11;
    int cnt = counts[m];
    if (cnt > MAXC) cnt = MAXC;
    float accT = tail_emd[(size_t)m * 128 + d];
    float accH = 0.f;
    float qhd = qh[b * 128 + d];
    for (int jj = 0; jj < cnt; ++jj) {
      int e = lists[m * MAXC + jj];
      float a = attw[e];
      size_t eo = (size_t)e * 128 + d;
      accT += a * (qhd + r[eo] + tm[eo]);
      accH += hidden[eo];
    }
    es[j + sub][d] = accT;
    out_hid[(size_t)row * 128 + d] = accH;
  }
  __syncthreads();
  // ---- phase 2: GEMM es(16x128) @ Wout(128x128) ----
  int cg = tid & 31;   // columns cg*4 .. cg*4+3
  int rg = tid >> 5;   // row pair rg*2, rg*2+1
  float4 bo = *(const float4*)(bout + cg * 4);
  float acc0x = bo.x, acc0y = bo.y, acc0z = bo.z, acc0w = bo.w;
  float acc1x = bo.x, acc1y = bo.y, acc1z = bo.z, acc1w = bo.w;
#pragma unroll 4
  for (int i = 0; i < 128; ++i) {
    float4 w = *(const float4*)(Wout + i * 128 + cg * 4);
    float e0 = es[rg * 2 + 0][i];
    float e1 = es[rg * 2 + 1][i];
    acc0x += e0 * w.x; acc0y += e0 * w.y; acc0z += e0 * w.z; acc0w += e0 * w.w;
    acc1x += e1 * w.x; acc1y += e1 * w.y; acc1z += e1 * w.z; acc1w += e1 * w.w;
  }
  size_t r0 = (size_t)(base + rg * 2) * 128 + cg * 4;
  *(float4*)(out_emd + r0) = make_float4(acc0x, acc0y, acc0z, acc0w);
  *(float4*)(out_emd + r0 + 128) = make_float4(acc1x, acc1y, acc1z, acc1w);
}

// ---------------------------------------------------------------------------
extern "C" void kernel_launch(void* const* d_in, const int* in_sizes, int n_in,
                              void* d_out, int out_size, void* d_ws,
                              size_t ws_size, hipStream_t stream) {
  const float* q_head = (const float*)d_in[0];
  const float* q_rel = (const float*)d_in[1];
  const float* q_time = (const float*)d_in[2];
  const float* r_nb = (const float*)d_in[3];
  const float* t_nb = (const float*)d_in[4];
  const float* tm_nb = (const float*)d_in[5];
  const float* hidden = (const float*)d_in[6];
  const float* tail_emd = (const float*)d_in[7];
  const int* tail_index = (const int*)d_in[8];
  const int* tail_nodes = (const int*)d_in[9];
  const float* W_q = (const float*)d_in[10];
  const float* b_q = (const float*)d_in[11];
  const float* W_a = (const float*)d_in[12];
  const float* b_a = (const float*)d_in[13];
  const float* W_att = (const float*)d_in[14];
  const float* b_att = (const float*)d_in[15];
  const float* W_rule = (const float*)d_in[16];
  const float* b_rule = (const float*)d_in[17];
  const float* W_out = (const float*)d_in[18];
  const float* b_out = (const float*)d_in[19];

  char* ws = (char*)d_ws;
  float* vf = (float*)(ws + 0);              // 32*384*4 = 49152
  float* c2f = (float*)(ws + 49152);         // 128 -> pad 49280
  float* attw = (float*)(ws + 49280);        // E*4 = 524288 -> 573568
  int* counts = (int*)(ws + 573568);         // M*4 = 262144 -> 835712
  int* lists = (int*)(ws + 835712);          // M*32*4 = 8388608 -> 9224320
  double* aggd = (double*)(ws + 9224320);    // M*8 = 524288 -> 9748608
  int* idxw = (int*)(ws + 9748608);          // B*K*4 = 65536 -> 9814144

  float* out_nodes = (float*)d_out;                       // B*K*2
  float* out_emd = (float*)d_out + (size_t)B * KTOP * 2;  // B*K*128
  float* out_hid = out_emd + (size_t)B * KTOP * 128;      // B*K*128

  hipMemsetAsync(counts, 0, MSEG * sizeof(int), stream);
  hipMemsetAsync(aggd, 0, MSEG * sizeof(double), stream);
  k0_precompute<<<B, 128, 0, stream>>>(q_head, q_rel, q_time, W_q, b_q, W_a,
                                       b_a, W_att, b_att, vf, c2f);
  k1_att<<<E / 64, 256, 0, stream>>>(r_nb, t_nb, tm_nb, hidden, W_rule, b_rule,
                                     vf, c2f, tail_index, attw, aggd);
  kb_build<<<E / 256, 256, 0, stream>>>(tail_index, counts, lists);
  k6_topk<<<B * 8, 256, 0, stream>>>(aggd, tail_nodes, out_nodes, idxw);
  k7_out<<<(B * KTOP) / K7ROWS, 256, 0, stream>>>(tail_emd, r_nb, tm_nb,
                                                  hidden, q_head, attw, counts,
                                                  lists, W_out, b_out, idxw,
                                                  out_emd, out_hid);
}